// Round 14
// baseline (2749.663 us; speedup 1.0000x reference)
//
#include <hip/hip_runtime.h>
#include <hip/hip_fp16.h>

typedef _Float16 f16;
typedef unsigned int u32;
typedef unsigned short u16;
typedef unsigned long long u64;
typedef _Float16 f16x8 __attribute__((ext_vector_type(8)));
typedef float f32x4 __attribute__((ext_vector_type(4)));

#define B_ 64
#define T_ 512
#define I_ 512
#define H_ 1024
#define HB_ (B_ * H_)
#define NWG_ 192
#define RS_ 32768      // u32 per h-ring slot (64 rows x 1024 cols f16)
#define XS16_ 65536    // u16 (f16) per xp1 slot

// ---- agent-scope (LLC-coherent) helpers ----
__device__ __forceinline__ u64 lda64(const u32* p) {
    return __hip_atomic_load((const u64*)p, __ATOMIC_RELAXED, __HIP_MEMORY_SCOPE_AGENT);
}
__device__ __forceinline__ void sta16(u16* p, u16 v) {
    __hip_atomic_store(p, v, __ATOMIC_RELAXED, __HIP_MEMORY_SCOPE_AGENT);
}
__device__ __forceinline__ void stflag(int* p, int v) {
    __hip_atomic_store(p, v, __ATOMIC_RELAXED, __HIP_MEMORY_SCOPE_AGENT);
}
__device__ __forceinline__ float ldxf16(const u16* p) {
    u16 v = __hip_atomic_load(p, __ATOMIC_RELAXED, __HIP_MEMORY_SCOPE_AGENT);
    return (float)__builtin_bit_cast(f16, v);
}

// ---- pipelined fast poll (r12-proven): 4 in-flight uncached loads, check
// oldest each iteration (detect quantization ~ RTT/4). Guard -> visible fail.
__device__ __forceinline__ void fastpoll(const int* p, int thr) {
    int f0, f1, f2, f3; int g = 0;
    asm volatile(
        "global_load_dword %[a], %[q], off sc0 sc1\n\t"
        "global_load_dword %[b], %[q], off sc0 sc1\n\t"
        "global_load_dword %[c], %[q], off sc0 sc1\n\t"
        "global_load_dword %[d], %[q], off sc0 sc1\n\t"
        "1:\n\t"
        "s_add_u32 %[g], %[g], 1\n\t"
        "s_cmp_gt_u32 %[g], 0x400000\n\t"
        "s_cbranch_scc1 2f\n\t"
        "s_waitcnt vmcnt(3)\n\t"
        "v_cmp_lt_i32 vcc, %[a], %[t]\n\t"
        "global_load_dword %[a], %[q], off sc0 sc1\n\t"
        "s_cbranch_vccz 2f\n\t"
        "s_waitcnt vmcnt(3)\n\t"
        "v_cmp_lt_i32 vcc, %[b], %[t]\n\t"
        "global_load_dword %[b], %[q], off sc0 sc1\n\t"
        "s_cbranch_vccz 2f\n\t"
        "s_waitcnt vmcnt(3)\n\t"
        "v_cmp_lt_i32 vcc, %[c], %[t]\n\t"
        "global_load_dword %[c], %[q], off sc0 sc1\n\t"
        "s_cbranch_vccz 2f\n\t"
        "s_waitcnt vmcnt(3)\n\t"
        "v_cmp_lt_i32 vcc, %[d], %[t]\n\t"
        "global_load_dword %[d], %[q], off sc0 sc1\n\t"
        "s_cbranch_vccnz 1b\n\t"
        "2:\n\t"
        "s_waitcnt vmcnt(0)\n\t"
        : [a]"=&v"(f0), [b]"=&v"(f1), [c]"=&v"(f2), [d]"=&v"(f3), [g]"+s"(g)
        : [q]"v"(p), [t]"v"(thr)
        : "vcc", "memory");
}

// fragment-linear single-f16 ring layout (r12-proven):
// (row b, col n): mi=b>>4, rl=b&15, kwin=n>>8, krem=n&255, it=krem>>5,
// k32=krem&31, kq3=k32>>3, k8=k32&7
// u32 idx = ((mi*4+kwin)*8+it)*256 + (k8>>2)*128 + kq3*32 + rl*2 + ((k8>>1)&1); f16 at 2*idx+(k8&1)
__global__ void init_rings(const float* __restrict__ h0,
                           u16* __restrict__ ring0, u16* __restrict__ ring1) {
    int i = blockIdx.x * blockDim.x + threadIdx.x;   // 0..HB_-1
    int b = i >> 10, n = i & 1023;
    int mi = b >> 4, rl = b & 15;
    int kwin = n >> 8, krem = n & 255;
    int it = krem >> 5, k32 = krem & 31;
    int kq3 = k32 >> 3, k8 = k32 & 7;
    int idx = (((mi*4 + kwin)*8 + it)*256 + (k8>>2)*128 + kq3*32 + rl*2 + ((k8>>1)&1))*2 + (k8&1);
    ring0[3*RS_*2 + idx] = __builtin_bit_cast(u16, (f16)h0[i]);        // slot ts=-1
    ring1[3*RS_*2 + idx] = __builtin_bit_cast(u16, (f16)h0[HB_ + i]);
}

// ---------------- xproj0 GEMM: f32 inputs, 8 n-tiles per wave ----------------
__global__ __launch_bounds__(256) void gemm_xproj(
    const float* __restrict__ A, const float* __restrict__ W,
    const float* __restrict__ bias, f16* __restrict__ out)
{
    const int wave = threadIdx.x >> 6, lane = threadIdx.x & 63;
    const int m0 = blockIdx.x << 4;
    const int r = lane & 15, kq = lane >> 4;
    const int ngrp = (blockIdx.y << 9) + (wave << 7);   // 128 cols per wave
    const float* pa = A + (long)(m0 + r) * I_ + kq * 8;
    const float* pw = W + (long)(ngrp + r) * I_ + kq * 8;

    f32x4 acc[8] = {};
    #pragma unroll
    for (int kc = 0; kc < I_; kc += 32) {
        float4 a0 = *reinterpret_cast<const float4*>(pa + kc);
        float4 a1 = *reinterpret_cast<const float4*>(pa + kc + 4);
        f16x8 af = { (f16)a0.x, (f16)a0.y, (f16)a0.z, (f16)a0.w,
                     (f16)a1.x, (f16)a1.y, (f16)a1.z, (f16)a1.w };
        #pragma unroll
        for (int t = 0; t < 8; ++t) {
            const float* pwt = pw + (long)t * 16 * I_ + kc;
            float4 w0 = *reinterpret_cast<const float4*>(pwt);
            float4 w1 = *reinterpret_cast<const float4*>(pwt + 4);
            f16x8 wf = { (f16)w0.x, (f16)w0.y, (f16)w0.z, (f16)w0.w,
                         (f16)w1.x, (f16)w1.y, (f16)w1.z, (f16)w1.w };
            acc[t] = __builtin_amdgcn_mfma_f32_16x16x32_f16(af, wf, acc[t], 0, 0, 0);
        }
    }
    const int col = lane & 15, rq = lane >> 4;
    #pragma unroll
    for (int t = 0; t < 8; ++t) {
        const int n = ngrp + t * 16 + col;
        const float bv = bias[n];
        #pragma unroll
        for (int j = 0; j < 4; ++j)
            out[(long)(m0 + rq * 4 + j) * H_ + n] = (f16)(acc[t][j] + bv);
    }
}

// ---------------- persistent dataflow scan ----------------
// Identical structure to the passing round-12/13 kernels. Changes vs r13:
//  (a) poll reverted to r12's 4-deep no-sleep fastpoll (r13's sleep regressed)
//  (b) W staged into LDS directly from f32 inputs (cvt kernels eliminated)
// xp1 stays f16 (r13's byte cut, kept).
__global__ void __launch_bounds__(256, 1) rnn_scan(
    const float* __restrict__ Whh0, const float* __restrict__ Wxh1, const float* __restrict__ Whh1,
    const f16* __restrict__ xp0, const float* __restrict__ b1,
    u32* __restrict__ ring0, u32* __restrict__ ring1, u16* __restrict__ xp1,
    float* __restrict__ out, int* __restrict__ flags)
{
    extern __shared__ char smem[];                 // 128 KB W + 16 KB part
    float* part = (float*)(smem + 131072);

    const int tid = threadIdx.x;
    const int wave = tid >> 6, lane = tid & 63;
    const int wg = blockIdx.x;
    const int grp = wg >> 6, sub = wg & 63;
    const int mi = sub & 3, ct = sub >> 2;
    const int m0 = mi << 4;
    const int nbase = ct << 6;
    const int r = lane & 15, kq = lane >> 4;

    int* fAw = flags;               // [4][16][4] stride 32 (per-wave, grp0 h0)
    int* fEw = flags + 8192;        // per-wave, grp2 h1
    int* fCw = flags + 16384;       // per-wave, grp1 xp1
    int* fB  = flags + 24576;       // WG-level: grp1 consumed h0
    int* fD  = flags + 26624;       // WG-level: grp2 consumed xp1
    const int mb4 = mi * 16;

    const float* Wmat = (grp == 0) ? Whh0 : (grp == 1) ? Wxh1 : Whh1;

    // ---- one-time: stage W slice (f32 -> f16) into LDS (swizzled 16B chunks) ----
    for (int i = 0; i < 32; ++i) {
        int idx = tid + (i << 8);
        int row = idx >> 7, c = idx & 127;
        const float* src = Wmat + (long)(nbase + row) * H_ + (c << 3);
        float4 w0 = *reinterpret_cast<const float4*>(src);
        float4 w1 = *reinterpret_cast<const float4*>(src + 4);
        f16x8 wf = { (f16)w0.x, (f16)w0.y, (f16)w0.z, (f16)w0.w,
                     (f16)w1.x, (f16)w1.y, (f16)w1.z, (f16)w1.w };
        *reinterpret_cast<f16x8*>(smem + row * 2048 + ((c ^ (row & 7)) << 4)) = wf;
    }
    __syncthreads();

    const int nf = nbase + (wave << 4) + r;        // finalize column
    const float b1v = (grp == 1) ? b1[nf] : 0.f;

    // producer f16 store base (u16 index within slot), + (kq*4+j)*4 per row
    const int kwin_s = nf >> 8, krem_s = nf & 255;
    const int it_s = krem_s >> 5, k32_s = krem_s & 31;
    const int kq3_s = k32_s >> 3, k8_s = k32_s & 7;
    const int base16 = (((mi*4 + kwin_s)*8 + it_s)*256 + (k8_s>>2)*128 + kq3_s*32 + ((k8_s>>1)&1))*2 + (k8_s&1);

    // consumer ring-load base (u32): wave's k-window, lane-linear
    const int cBase = (mi * 4 + wave) * 2048 + (lane << 1);

    // ---- per-lane poll target (constant across steps; threshold = ts + poll_d) ----
    const int idx16 = lane & 15;
    const int ctp = (wave << 2) + (idx16 >> 2);
    const int wvp = idx16 & 3;
    const int myflag = ((mb4 + ct) * 4 + wave) * 32;
    const int* poll_p; int poll_d;
    if (grp == 0) {
        if (lane < 16)      { poll_p = fAw + ((mb4 + ctp) * 4 + wvp) * 32; poll_d = 0; }
        else if (lane < 32) { poll_p = fB + (mb4 + idx16) * 32;            poll_d = -3; }
        else                { poll_p = fAw + myflag;                        poll_d = -1000000; }
    } else if (grp == 1) {
        if (lane < 16)      { poll_p = fAw + ((mb4 + ctp) * 4 + wvp) * 32; poll_d = 1; }
        else if (lane == 16){ poll_p = fD + (mb4 + ct) * 32;               poll_d = -3; }
        else                { poll_p = fCw + myflag;                        poll_d = -1000000; }
    } else {
        if (lane < 16)      { poll_p = fEw + ((mb4 + ctp) * 4 + wvp) * 32; poll_d = 0; }
        else if (lane == 16){ poll_p = fCw + ((mb4 + ct) * 4 + wave) * 32; poll_d = 1; }
        else                { poll_p = fEw + myflag;                        poll_d = -1000000; }
    }

    for (int ts = 0; ts < T_; ++ts) {
        float xv[4];
        // xp0 prefetch (read-only, independent of producers) BEFORE the wait
        if (grp == 0) {
            #pragma unroll
            for (int j = 0; j < 4; ++j)
                xv[j] = (float)xp0[((long)(m0 + kq * 4 + j) * T_ + ts) * H_ + nf];
        } else {
            #pragma unroll
            for (int j = 0; j < 4; ++j) xv[j] = 0.f;
        }

        // ---- per-wave dataflow wait (pipelined fast poll) ----
        fastpoll(poll_p, ts + poll_d);
        __builtin_amdgcn_sched_barrier(0);

        const u32* ringA;
        if (grp == 0)      ringA = ring0 + ((ts - 1) & 3) * RS_;
        else if (grp == 1) ringA = ring0 + (ts & 3) * RS_;
        else               ringA = ring1 + ((ts - 1) & 3) * RS_;

        if (grp == 2) {
            #pragma unroll
            for (int j = 0; j < 4; ++j)
                xv[j] = ldxf16(xp1 + (ts & 3) * XS16_ + (m0 + kq * 4 + j) * 1024 + nf);
        }

        // ring loads: fragment-linear, fully coalesced (64 lanes x 8B contiguous)
        const u32* abase = ringA + cBase;
        u64 q[8][2];
        #pragma unroll
        for (int it = 0; it < 8; ++it) {
            q[it][0] = lda64(abase + it * 256);
            q[it][1] = lda64(abase + it * 256 + 128);
        }

        f16x8 ah[8];
        #pragma unroll
        for (int it = 0; it < 8; ++it) {
            u32 w0 = (u32)q[it][0], w1 = (u32)(q[it][0] >> 32);
            u32 w2 = (u32)q[it][1], w3 = (u32)(q[it][1] >> 32);
            ah[it][0] = __builtin_bit_cast(f16, (u16)(w0 & 0xffff));
            ah[it][1] = __builtin_bit_cast(f16, (u16)(w0 >> 16));
            ah[it][2] = __builtin_bit_cast(f16, (u16)(w1 & 0xffff));
            ah[it][3] = __builtin_bit_cast(f16, (u16)(w1 >> 16));
            ah[it][4] = __builtin_bit_cast(f16, (u16)(w2 & 0xffff));
            ah[it][5] = __builtin_bit_cast(f16, (u16)(w2 >> 16));
            ah[it][6] = __builtin_bit_cast(f16, (u16)(w3 & 0xffff));
            ah[it][7] = __builtin_bit_cast(f16, (u16)(w3 >> 16));
        }
        asm volatile("s_waitcnt vmcnt(0)" ::: "memory");
        __builtin_amdgcn_sched_barrier(0);

        f32x4 acc[4] = {};
        #pragma unroll
        for (int it = 0; it < 8; ++it) {
            #pragma unroll
            for (int t = 0; t < 4; ++t) {
                f16x8 wf = *reinterpret_cast<const f16x8*>(
                    smem + (t * 16 + r) * 2048
                         + ((((wave << 5) + (it << 2) + kq) ^ (r & 7)) << 4));
                acc[t] = __builtin_amdgcn_mfma_f32_16x16x32_f16(ah[it], wf, acc[t], 0, 0, 0);
            }
        }
        #pragma unroll
        for (int t = 0; t < 4; ++t)
            *reinterpret_cast<f32x4*>(&part[((wave << 2) + t) * 256 + (lane << 2)]) = acc[t];
        __syncthreads();

        // WAR publishes (loads provably drained: every wave passed vmcnt(0))
        if (tid == 0) {
            if (grp == 1)      stflag(fB + (mb4 + ct) * 32, ts + 1);
            else if (grp == 2) stflag(fD + (mb4 + ct) * 32, ts + 1);
        }

        {
            f32x4 sm = *reinterpret_cast<f32x4*>(&part[wave * 256 + (lane << 2)]);
            #pragma unroll
            for (int w2 = 1; w2 < 4; ++w2)
                sm = sm + *reinterpret_cast<f32x4*>(&part[((w2 << 2) + wave) * 256 + (lane << 2)]);
            #pragma unroll
            for (int j = 0; j < 4; ++j) {
                const int b = m0 + kq * 4 + j;
                float v = sm[j];
                if (grp == 0) {
                    v = tanhf(v + xv[j]);
                    sta16((u16*)ring0 + (ts & 3) * RS_ * 2 + base16 + (kq * 4 + j) * 4,
                          __builtin_bit_cast(u16, (f16)v));
                    if (ts == T_ - 1) out[(long)B_ * T_ * H_ + (long)b * H_ + nf] = v;
                } else if (grp == 1) {
                    sta16(xp1 + (ts & 3) * XS16_ + b * 1024 + nf,
                          __builtin_bit_cast(u16, (f16)(v + b1v)));
                } else {
                    v = tanhf(v + xv[j]);
                    sta16((u16*)ring1 + (ts & 3) * RS_ * 2 + base16 + (kq * 4 + j) * 4,
                          __builtin_bit_cast(u16, (f16)v));
                    out[((long)b * T_ + ts) * H_ + nf] = v;
                    if (ts == T_ - 1) out[(long)B_ * T_ * H_ + HB_ + (long)b * H_ + nf] = v;
                }
            }
        }
        // ---- per-wave drain + per-wave produce flag (proven ordering) ----
        asm volatile("s_waitcnt vmcnt(0)" ::: "memory");
        if (lane == 0) {
            if (grp == 0)      stflag(fAw + myflag, ts + 1);
            else if (grp == 1) stflag(fCw + myflag, ts + 1);
            else               stflag(fEw + myflag, ts + 1);
        }
        __syncthreads();   // LDS part[] reuse safety (off consumer critical path)
    }
}

// ---------------- host launcher ----------------
extern "C" void kernel_launch(void* const* d_in, const int* in_sizes, int n_in,
                              void* d_out, int out_size, void* d_ws, size_t ws_size,
                              hipStream_t stream) {
    const float* x    = (const float*)d_in[0];
    const float* h0   = (const float*)d_in[1];
    const float* Wxh0 = (const float*)d_in[2];
    const float* Whh0 = (const float*)d_in[3];
    const float* b0   = (const float*)d_in[4];
    const float* Wxh1 = (const float*)d_in[5];
    const float* Whh1 = (const float*)d_in[6];
    const float* b1   = (const float*)d_in[7];
    float* out = (float*)d_out;

    char* ws = (char*)d_ws;
    const long MB = 1024 * 1024;
    int* flags = (int*)(ws + 7*MB);         // flag regions (<128 KB)
    u32* ring0 = (u32*)(ws + 8*MB);         // 4 slots x 128 KB = 512 KB
    u32* ring1 = (u32*)(ws + 9*MB);         // 512 KB
    u16* xp1   = (u16*)(ws + 10*MB);        // 4 slots x 128 KB f16 = 512 KB
    f16* xp0   = (f16*)(ws + 16*MB);        // [B][T][H] f16, 64 MB

    init_rings<<<HB_/256, 256, 0, stream>>>(h0, (u16*)ring0, (u16*)ring1);
    hipMemsetAsync(flags, 0, 128*1024, stream);

    // xp0 = x @ Wxh0^T + b0   (f32 inputs, f16 out; row index = b*T + t)
    gemm_xproj<<<dim3((B_*T_)/16, H_/512), 256, 0, stream>>>(x, Wxh0, b0, xp0);

    hipFuncSetAttribute((const void*)rnn_scan,
                        hipFuncAttributeMaxDynamicSharedMemorySize, 147456);

    void* args[] = { (void*)&Whh0, (void*)&Wxh1, (void*)&Whh1, (void*)&xp0,
                     (void*)&b1, (void*)&ring0, (void*)&ring1, (void*)&xp1,
                     (void*)&out, (void*)&flags };
    hipLaunchCooperativeKernel((void*)rnn_scan, dim3(NWG_), dim3(256), args,
                               147456, stream);
}

// Round 15
// 2293.743 us; speedup vs baseline: 1.1988x; 1.1988x over previous
//
#include <hip/hip_runtime.h>
#include <hip/hip_fp16.h>

typedef _Float16 f16;
typedef unsigned int u32;
typedef unsigned short u16;
typedef unsigned long long u64;
typedef _Float16 f16x8 __attribute__((ext_vector_type(8)));
typedef float f32x4 __attribute__((ext_vector_type(4)));

#define B_ 64
#define T_ 512
#define I_ 512
#define H_ 1024
#define HB_ (B_ * H_)
#define NWG_ 192
#define RS_ 32768      // u32 per h-ring slot (64 rows x 1024 cols f16)
#define XS_ 65536      // f32 per xp1 slot

// ---- agent-scope (LLC-coherent) helpers ----
__device__ __forceinline__ u64 lda64(const u32* p) {
    return __hip_atomic_load((const u64*)p, __ATOMIC_RELAXED, __HIP_MEMORY_SCOPE_AGENT);
}
__device__ __forceinline__ u32 lda32(const u32* p) {
    return __hip_atomic_load(p, __ATOMIC_RELAXED, __HIP_MEMORY_SCOPE_AGENT);
}
__device__ __forceinline__ void sta32(u32* p, u32 v) {
    __hip_atomic_store(p, v, __ATOMIC_RELAXED, __HIP_MEMORY_SCOPE_AGENT);
}
__device__ __forceinline__ void sta16(u16* p, u16 v) {
    __hip_atomic_store(p, v, __ATOMIC_RELAXED, __HIP_MEMORY_SCOPE_AGENT);
}
__device__ __forceinline__ void stflag(int* p, int v) {
    __hip_atomic_store(p, v, __ATOMIC_RELAXED, __HIP_MEMORY_SCOPE_AGENT);
}

// ---- pipelined fast poll (r12-proven): 4 in-flight uncached loads, check
// oldest each iteration (detect quantization ~ RTT/4). Guard -> visible fail.
__device__ __forceinline__ void fastpoll(const int* p, int thr) {
    int f0, f1, f2, f3; int g = 0;
    asm volatile(
        "global_load_dword %[a], %[q], off sc0 sc1\n\t"
        "global_load_dword %[b], %[q], off sc0 sc1\n\t"
        "global_load_dword %[c], %[q], off sc0 sc1\n\t"
        "global_load_dword %[d], %[q], off sc0 sc1\n\t"
        "1:\n\t"
        "s_add_u32 %[g], %[g], 1\n\t"
        "s_cmp_gt_u32 %[g], 0x400000\n\t"
        "s_cbranch_scc1 2f\n\t"
        "s_waitcnt vmcnt(3)\n\t"
        "v_cmp_lt_i32 vcc, %[a], %[t]\n\t"
        "global_load_dword %[a], %[q], off sc0 sc1\n\t"
        "s_cbranch_vccz 2f\n\t"
        "s_waitcnt vmcnt(3)\n\t"
        "v_cmp_lt_i32 vcc, %[b], %[t]\n\t"
        "global_load_dword %[b], %[q], off sc0 sc1\n\t"
        "s_cbranch_vccz 2f\n\t"
        "s_waitcnt vmcnt(3)\n\t"
        "v_cmp_lt_i32 vcc, %[c], %[t]\n\t"
        "global_load_dword %[c], %[q], off sc0 sc1\n\t"
        "s_cbranch_vccz 2f\n\t"
        "s_waitcnt vmcnt(3)\n\t"
        "v_cmp_lt_i32 vcc, %[d], %[t]\n\t"
        "global_load_dword %[d], %[q], off sc0 sc1\n\t"
        "s_cbranch_vccnz 1b\n\t"
        "2:\n\t"
        "s_waitcnt vmcnt(0)\n\t"
        : [a]"=&v"(f0), [b]"=&v"(f1), [c]"=&v"(f2), [d]"=&v"(f3), [g]"+s"(g)
        : [q]"v"(p), [t]"v"(thr)
        : "vcc", "memory");
}

// ---------------- conversion kernel (weights only; x stays f32) ----------------
__global__ void cvt_f16(const float* __restrict__ s, f16* __restrict__ d, long n) {
    long i = ((long)blockIdx.x * blockDim.x + threadIdx.x) * 4;
    long stride = (long)gridDim.x * blockDim.x * 4;
    for (; i < n; i += stride) {
        float4 v = *reinterpret_cast<const float4*>(s + i);
        d[i+0] = (f16)v.x; d[i+1] = (f16)v.y; d[i+2] = (f16)v.z; d[i+3] = (f16)v.w;
    }
}

// fragment-linear single-f16 ring layout (r12-proven):
// (row b, col n): mi=b>>4, rl=b&15, kwin=n>>8, krem=n&255, it=krem>>5,
// k32=krem&31, kq3=k32>>3, k8=k32&7
// u32 idx = ((mi*4+kwin)*8+it)*256 + (k8>>2)*128 + kq3*32 + rl*2 + ((k8>>1)&1); f16 at 2*idx+(k8&1)
__global__ void init_rings(const float* __restrict__ h0,
                           u16* __restrict__ ring0, u16* __restrict__ ring1) {
    int i = blockIdx.x * blockDim.x + threadIdx.x;   // 0..HB_-1
    int b = i >> 10, n = i & 1023;
    int mi = b >> 4, rl = b & 15;
    int kwin = n >> 8, krem = n & 255;
    int it = krem >> 5, k32 = krem & 31;
    int kq3 = k32 >> 3, k8 = k32 & 7;
    int idx = (((mi*4 + kwin)*8 + it)*256 + (k8>>2)*128 + kq3*32 + rl*2 + ((k8>>1)&1))*2 + (k8&1);
    ring0[3*RS_*2 + idx] = __builtin_bit_cast(u16, (f16)h0[i]);        // slot ts=-1
    ring1[3*RS_*2 + idx] = __builtin_bit_cast(u16, (f16)h0[HB_ + i]);
}

// ---------------- xproj0 GEMM: f32 A (in-register cvt, once/element/block),
// pre-cvt'd f16 W, 8 n-tiles per wave ----------------
__global__ __launch_bounds__(256) void gemm_xproj(
    const float* __restrict__ A, const f16* __restrict__ W,
    const float* __restrict__ bias, f16* __restrict__ out)
{
    const int wave = threadIdx.x >> 6, lane = threadIdx.x & 63;
    const int m0 = blockIdx.x << 4;
    const int r = lane & 15, kq = lane >> 4;
    const int ngrp = (blockIdx.y << 9) + (wave << 7);   // 128 cols per wave
    const float* pa = A + (long)(m0 + r) * I_ + kq * 8;
    const f16*   pw = W + (long)(ngrp + r) * I_ + kq * 8;

    f32x4 acc[8] = {};
    #pragma unroll
    for (int kc = 0; kc < I_; kc += 32) {
        float4 a0 = *reinterpret_cast<const float4*>(pa + kc);
        float4 a1 = *reinterpret_cast<const float4*>(pa + kc + 4);
        f16x8 af = { (f16)a0.x, (f16)a0.y, (f16)a0.z, (f16)a0.w,
                     (f16)a1.x, (f16)a1.y, (f16)a1.z, (f16)a1.w };
        #pragma unroll
        for (int t = 0; t < 8; ++t) {
            f16x8 wf = *reinterpret_cast<const f16x8*>(pw + (long)t * 16 * I_ + kc);
            acc[t] = __builtin_amdgcn_mfma_f32_16x16x32_f16(af, wf, acc[t], 0, 0, 0);
        }
    }
    const int col = lane & 15, rq = lane >> 4;
    #pragma unroll
    for (int t = 0; t < 8; ++t) {
        const int n = ngrp + t * 16 + col;
        const float bv = bias[n];
        #pragma unroll
        for (int j = 0; j < 4; ++j)
            out[(long)(m0 + rq * 4 + j) * H_ + n] = (f16)(acc[t][j] + bv);
    }
}

// ---------------- persistent dataflow scan (r12 verbatim) ----------------
// 192 WGs x 256 threads, 3 groups of 64 (grp = wg>>6, sub = wg&63):
//   grp0 (mi,ct): h0[ts]  = tanh(xp0[ts] + h0[ts-1]@Whh0^T)
//   grp1 (mi,ct): xp1[ts] = h0[ts]@Wxh1^T + b1
//   grp2 (mi,ct): h1[ts]  = tanh(xp1[ts] + h1[ts-1]@Whh1^T)
// h rings: single f16, fragment-linear (coalesced u64 consumer loads).
// xp1: f32 (r13/r14 showed f16 here REGRESSES ~0.5 us/step - sub-word UC ops).
// All cross-step traffic relaxed agent atomics; wave-level flags; fastpoll-4.
__global__ void __launch_bounds__(256, 1) rnn_scan(
    const f16* __restrict__ Whh0, const f16* __restrict__ Wxh1, const f16* __restrict__ Whh1,
    const f16* __restrict__ xp0, const float* __restrict__ b1,
    u32* __restrict__ ring0, u32* __restrict__ ring1, u32* __restrict__ xp1,
    float* __restrict__ out, int* __restrict__ flags)
{
    extern __shared__ char smem[];                 // 128 KB W + 16 KB part
    float* part = (float*)(smem + 131072);

    const int tid = threadIdx.x;
    const int wave = tid >> 6, lane = tid & 63;
    const int wg = blockIdx.x;
    const int grp = wg >> 6, sub = wg & 63;
    const int mi = sub & 3, ct = sub >> 2;
    const int m0 = mi << 4;
    const int nbase = ct << 6;
    const int r = lane & 15, kq = lane >> 4;

    int* fAw = flags;               // [4][16][4] stride 32 (per-wave, grp0 h0)
    int* fEw = flags + 8192;        // per-wave, grp2 h1
    int* fCw = flags + 16384;       // per-wave, grp1 xp1
    int* fB  = flags + 24576;       // WG-level: grp1 consumed h0
    int* fD  = flags + 26624;       // WG-level: grp2 consumed xp1
    const int mb4 = mi * 16;

    const f16* Wmat = (grp == 0) ? Whh0 : (grp == 1) ? Wxh1 : Whh1;

    // ---- one-time: stage W slice into LDS (swizzled 16B chunks) ----
    for (int i = 0; i < 32; ++i) {
        int idx = tid + (i << 8);
        int row = idx >> 7, c = idx & 127;
        f32x4 v = *reinterpret_cast<const f32x4*>(Wmat + (long)(nbase + row) * H_ + (c << 3));
        *reinterpret_cast<f32x4*>(smem + row * 2048 + ((c ^ (row & 7)) << 4)) = v;
    }
    __syncthreads();

    const int nf = nbase + (wave << 4) + r;        // finalize column
    const float b1v = (grp == 1) ? b1[nf] : 0.f;

    // producer f16 store base (u16 index within slot), + (kq*4+j)*4 per row
    const int kwin_s = nf >> 8, krem_s = nf & 255;
    const int it_s = krem_s >> 5, k32_s = krem_s & 31;
    const int kq3_s = k32_s >> 3, k8_s = k32_s & 7;
    const int base16 = (((mi*4 + kwin_s)*8 + it_s)*256 + (k8_s>>2)*128 + kq3_s*32 + ((k8_s>>1)&1))*2 + (k8_s&1);

    // consumer ring-load base (u32): wave's k-window, lane-linear
    const int cBase = (mi * 4 + wave) * 2048 + (lane << 1);

    // ---- per-lane poll target (constant across steps; threshold = ts + poll_d) ----
    const int idx16 = lane & 15;
    const int ctp = (wave << 2) + (idx16 >> 2);
    const int wvp = idx16 & 3;
    const int myflag = ((mb4 + ct) * 4 + wave) * 32;
    const int* poll_p; int poll_d;
    if (grp == 0) {
        if (lane < 16)      { poll_p = fAw + ((mb4 + ctp) * 4 + wvp) * 32; poll_d = 0; }
        else if (lane < 32) { poll_p = fB + (mb4 + idx16) * 32;            poll_d = -3; }
        else                { poll_p = fAw + myflag;                        poll_d = -1000000; }
    } else if (grp == 1) {
        if (lane < 16)      { poll_p = fAw + ((mb4 + ctp) * 4 + wvp) * 32; poll_d = 1; }
        else if (lane == 16){ poll_p = fD + (mb4 + ct) * 32;               poll_d = -3; }
        else                { poll_p = fCw + myflag;                        poll_d = -1000000; }
    } else {
        if (lane < 16)      { poll_p = fEw + ((mb4 + ctp) * 4 + wvp) * 32; poll_d = 0; }
        else if (lane == 16){ poll_p = fCw + ((mb4 + ct) * 4 + wave) * 32; poll_d = 1; }
        else                { poll_p = fEw + myflag;                        poll_d = -1000000; }
    }

    for (int ts = 0; ts < T_; ++ts) {
        float xv[4];
        // xp0 prefetch (read-only, independent of producers) BEFORE the wait
        if (grp == 0) {
            #pragma unroll
            for (int j = 0; j < 4; ++j)
                xv[j] = (float)xp0[((long)(m0 + kq * 4 + j) * T_ + ts) * H_ + nf];
        } else {
            #pragma unroll
            for (int j = 0; j < 4; ++j) xv[j] = 0.f;
        }

        // ---- per-wave dataflow wait (pipelined fast poll) ----
        fastpoll(poll_p, ts + poll_d);
        __builtin_amdgcn_sched_barrier(0);

        const u32* ringA;
        if (grp == 0)      ringA = ring0 + ((ts - 1) & 3) * RS_;
        else if (grp == 1) ringA = ring0 + (ts & 3) * RS_;
        else               ringA = ring1 + ((ts - 1) & 3) * RS_;

        if (grp == 2) {
            #pragma unroll
            for (int j = 0; j < 4; ++j)
                xv[j] = __builtin_bit_cast(float,
                    lda32(xp1 + (ts & 3) * XS_ + (m0 + kq * 4 + j) * 1024 + nf));
        }

        // ring loads: fragment-linear, fully coalesced (64 lanes x 8B contiguous)
        const u32* abase = ringA + cBase;
        u64 q[8][2];
        #pragma unroll
        for (int it = 0; it < 8; ++it) {
            q[it][0] = lda64(abase + it * 256);
            q[it][1] = lda64(abase + it * 256 + 128);
        }

        f16x8 ah[8];
        #pragma unroll
        for (int it = 0; it < 8; ++it) {
            u32 w0 = (u32)q[it][0], w1 = (u32)(q[it][0] >> 32);
            u32 w2 = (u32)q[it][1], w3 = (u32)(q[it][1] >> 32);
            ah[it][0] = __builtin_bit_cast(f16, (u16)(w0 & 0xffff));
            ah[it][1] = __builtin_bit_cast(f16, (u16)(w0 >> 16));
            ah[it][2] = __builtin_bit_cast(f16, (u16)(w1 & 0xffff));
            ah[it][3] = __builtin_bit_cast(f16, (u16)(w1 >> 16));
            ah[it][4] = __builtin_bit_cast(f16, (u16)(w2 & 0xffff));
            ah[it][5] = __builtin_bit_cast(f16, (u16)(w2 >> 16));
            ah[it][6] = __builtin_bit_cast(f16, (u16)(w3 & 0xffff));
            ah[it][7] = __builtin_bit_cast(f16, (u16)(w3 >> 16));
        }
        asm volatile("s_waitcnt vmcnt(0)" ::: "memory");
        __builtin_amdgcn_sched_barrier(0);

        f32x4 acc[4] = {};
        #pragma unroll
        for (int it = 0; it < 8; ++it) {
            #pragma unroll
            for (int t = 0; t < 4; ++t) {
                f16x8 wf = *reinterpret_cast<const f16x8*>(
                    smem + (t * 16 + r) * 2048
                         + ((((wave << 5) + (it << 2) + kq) ^ (r & 7)) << 4));
                acc[t] = __builtin_amdgcn_mfma_f32_16x16x32_f16(ah[it], wf, acc[t], 0, 0, 0);
            }
        }
        #pragma unroll
        for (int t = 0; t < 4; ++t)
            *reinterpret_cast<f32x4*>(&part[((wave << 2) + t) * 256 + (lane << 2)]) = acc[t];
        __syncthreads();

        // WAR publishes (loads provably drained: every wave passed vmcnt(0))
        if (tid == 0) {
            if (grp == 1)      stflag(fB + (mb4 + ct) * 32, ts + 1);
            else if (grp == 2) stflag(fD + (mb4 + ct) * 32, ts + 1);
        }

        {
            f32x4 sm = *reinterpret_cast<f32x4*>(&part[wave * 256 + (lane << 2)]);
            #pragma unroll
            for (int w2 = 1; w2 < 4; ++w2)
                sm = sm + *reinterpret_cast<f32x4*>(&part[((w2 << 2) + wave) * 256 + (lane << 2)]);
            #pragma unroll
            for (int j = 0; j < 4; ++j) {
                const int b = m0 + kq * 4 + j;
                float v = sm[j];
                if (grp == 0) {
                    v = tanhf(v + xv[j]);
                    sta16((u16*)ring0 + (ts & 3) * RS_ * 2 + base16 + (kq * 4 + j) * 4,
                          __builtin_bit_cast(u16, (f16)v));
                    if (ts == T_ - 1) out[(long)B_ * T_ * H_ + (long)b * H_ + nf] = v;
                } else if (grp == 1) {
                    sta32(xp1 + (ts & 3) * XS_ + b * 1024 + nf, __builtin_bit_cast(u32, v + b1v));
                } else {
                    v = tanhf(v + xv[j]);
                    sta16((u16*)ring1 + (ts & 3) * RS_ * 2 + base16 + (kq * 4 + j) * 4,
                          __builtin_bit_cast(u16, (f16)v));
                    out[((long)b * T_ + ts) * H_ + nf] = v;
                    if (ts == T_ - 1) out[(long)B_ * T_ * H_ + HB_ + (long)b * H_ + nf] = v;
                }
            }
        }
        // ---- per-wave drain + per-wave produce flag (proven ordering) ----
        asm volatile("s_waitcnt vmcnt(0)" ::: "memory");
        if (lane == 0) {
            if (grp == 0)      stflag(fAw + myflag, ts + 1);
            else if (grp == 1) stflag(fCw + myflag, ts + 1);
            else               stflag(fEw + myflag, ts + 1);
        }
        __syncthreads();   // LDS part[] reuse safety (off consumer critical path)
    }
}

// ---------------- host launcher ----------------
extern "C" void kernel_launch(void* const* d_in, const int* in_sizes, int n_in,
                              void* d_out, int out_size, void* d_ws, size_t ws_size,
                              hipStream_t stream) {
    const float* x    = (const float*)d_in[0];
    const float* h0   = (const float*)d_in[1];
    const float* Wxh0 = (const float*)d_in[2];
    const float* Whh0 = (const float*)d_in[3];
    const float* b0   = (const float*)d_in[4];
    const float* Wxh1 = (const float*)d_in[5];
    const float* Whh1 = (const float*)d_in[6];
    const float* b1   = (const float*)d_in[7];
    float* out = (float*)d_out;

    char* ws = (char*)d_ws;
    const long MB = 1024 * 1024;
    f16* Whh0h = (f16*)(ws + 0);            // 2 MB
    f16* Wxh1h = (f16*)(ws + 2*MB);         // 2 MB
    f16* Whh1h = (f16*)(ws + 4*MB);         // 2 MB
    f16* Wxh0h = (f16*)(ws + 6*MB);         // 1 MB
    int* flags = (int*)(ws + 7*MB);         // flag regions (<128 KB)
    u32* ring0 = (u32*)(ws + 8*MB);         // 4 slots x 128 KB = 512 KB
    u32* ring1 = (u32*)(ws + 9*MB);         // 512 KB
    u32* xp1   = (u32*)(ws + 10*MB);        // 4 slots x 256 KB f32 = 1 MB
    f16* xp0   = (f16*)(ws + 16*MB);        // [B][T][H] f16, 64 MB

    cvt_f16<<<512, 256, 0, stream>>>(Whh0, Whh0h, (long)H_*H_);
    cvt_f16<<<512, 256, 0, stream>>>(Wxh1, Wxh1h, (long)H_*H_);
    cvt_f16<<<512, 256, 0, stream>>>(Whh1, Whh1h, (long)H_*H_);
    cvt_f16<<<512, 256, 0, stream>>>(Wxh0, Wxh0h, (long)H_*I_);
    init_rings<<<HB_/256, 256, 0, stream>>>(h0, (u16*)ring0, (u16*)ring1);
    hipMemsetAsync(flags, 0, 128*1024, stream);

    // xp0 = x @ Wxh0^T + b0   (f32 A in-register cvt, f16 W; row = b*T + t)
    gemm_xproj<<<dim3((B_*T_)/16, H_/512), 256, 0, stream>>>(x, Wxh0h, b0, xp0);

    hipFuncSetAttribute((const void*)rnn_scan,
                        hipFuncAttributeMaxDynamicSharedMemorySize, 147456);

    void* args[] = { (void*)&Whh0h, (void*)&Wxh1h, (void*)&Whh1h, (void*)&xp0,
                     (void*)&b1, (void*)&ring0, (void*)&ring1, (void*)&xp1,
                     (void*)&out, (void*)&flags };
    hipLaunchCooperativeKernel((void*)rnn_scan, dim3(NWG_), dim3(256), args,
                               147456, stream);
}

// Round 16
// 2218.583 us; speedup vs baseline: 1.2394x; 1.0339x over previous
//
#include <hip/hip_runtime.h>
#include <hip/hip_fp16.h>

typedef _Float16 f16;
typedef unsigned int u32;
typedef unsigned short u16;
typedef unsigned long long u64;
typedef _Float16 f16x8 __attribute__((ext_vector_type(8)));
typedef float f32x4 __attribute__((ext_vector_type(4)));

#define B_ 64
#define T_ 512
#define I_ 512
#define H_ 1024
#define HB_ (B_ * H_)
#define NWG_ 192
#define RS_ 32768      // u32 per h-ring slot (64 rows x 1024 cols f16)
#define XS_ 65536      // f32 per xp1 slot
#define NS_ 31         // slot mask (32 slots)
#define RL_ 8          // sentinel-reset lead (slots)

// ---- agent-scope (LLC-coherent) helpers ----
__device__ __forceinline__ u64 lda64(const u32* p) {
    return __hip_atomic_load((const u64*)p, __ATOMIC_RELAXED, __HIP_MEMORY_SCOPE_AGENT);
}
__device__ __forceinline__ u32 lda32(const u32* p) {
    return __hip_atomic_load(p, __ATOMIC_RELAXED, __HIP_MEMORY_SCOPE_AGENT);
}
__device__ __forceinline__ void sta32(u32* p, u32 v) {
    __hip_atomic_store(p, v, __ATOMIC_RELAXED, __HIP_MEMORY_SCOPE_AGENT);
}
__device__ __forceinline__ void sta16(u16* p, u16 v) {
    __hip_atomic_store(p, v, __ATOMIC_RELAXED, __HIP_MEMORY_SCOPE_AGENT);
}
__device__ __forceinline__ void stflag(int* p, int v) {
    __hip_atomic_store(p, v, __ATOMIC_RELAXED, __HIP_MEMORY_SCOPE_AGENT);
}
__device__ __forceinline__ int ldflag(const int* p) {
    return __hip_atomic_load(p, __ATOMIC_RELAXED, __HIP_MEMORY_SCOPE_AGENT);
}
// sentinel check: any f16 lane of the u64 == 0xFFFF (NaN; tanh output never hits it)
__device__ __forceinline__ u32 badq(u64 v) {
    u32 lo = (u32)v, hi = (u32)(v >> 32);
    u32 b = ((lo & 0xFFFFu) == 0xFFFFu) ? 1u : 0u;
    b |= ((lo >> 16) == 0xFFFFu) ? 1u : 0u;
    b |= ((hi & 0xFFFFu) == 0xFFFFu) ? 1u : 0u;
    b |= ((hi >> 16) == 0xFFFFu) ? 1u : 0u;
    return b;
}

// ---------------- conversion kernel (Wxh0 only, for the prologue GEMM) ----------------
__global__ void cvt_f16(const float* __restrict__ s, f16* __restrict__ d, long n) {
    long i = ((long)blockIdx.x * blockDim.x + threadIdx.x) * 4;
    long stride = (long)gridDim.x * blockDim.x * 4;
    for (; i < n; i += stride) {
        float4 v = *reinterpret_cast<const float4*>(s + i);
        d[i+0] = (f16)v.x; d[i+1] = (f16)v.y; d[i+2] = (f16)v.z; d[i+3] = (f16)v.w;
    }
}

// fragment-linear single-f16 ring layout (r12-proven):
// (row b, col n): mi=b>>4, rl=b&15, kwin=n>>8, krem=n&255, it=krem>>5,
// k32=krem&31, kq3=k32>>3, k8=k32&7
// u32 idx = ((mi*4+kwin)*8+it)*256 + (k8>>2)*128 + kq3*32 + rl*2 + ((k8>>1)&1); f16 at 2*idx+(k8&1)
__global__ void init_rings(const float* __restrict__ h0,
                           u16* __restrict__ ring0, u16* __restrict__ ring1) {
    int i = blockIdx.x * blockDim.x + threadIdx.x;   // 0..HB_-1
    int b = i >> 10, n = i & 1023;
    int mi = b >> 4, rl = b & 15;
    int kwin = n >> 8, krem = n & 255;
    int it = krem >> 5, k32 = krem & 31;
    int kq3 = k32 >> 3, k8 = k32 & 7;
    int idx = (((mi*4 + kwin)*8 + it)*256 + (k8>>2)*128 + kq3*32 + rl*2 + ((k8>>1)&1))*2 + (k8&1);
    ring0[NS_*RS_*2 + idx] = __builtin_bit_cast(u16, (f16)h0[i]);        // slot for ts=-1 ((-1)&31=31)
    ring1[NS_*RS_*2 + idx] = __builtin_bit_cast(u16, (f16)h0[HB_ + i]);
}

// ---------------- xproj0 GEMM (r15-proven): f32 A in-register cvt, f16 W, 8 n-tiles/wave ----------------
__global__ __launch_bounds__(256) void gemm_xproj(
    const float* __restrict__ A, const f16* __restrict__ W,
    const float* __restrict__ bias, f16* __restrict__ out)
{
    const int wave = threadIdx.x >> 6, lane = threadIdx.x & 63;
    const int m0 = blockIdx.x << 4;
    const int r = lane & 15, kq = lane >> 4;
    const int ngrp = (blockIdx.y << 9) + (wave << 7);   // 128 cols per wave
    const float* pa = A + (long)(m0 + r) * I_ + kq * 8;
    const f16*   pw = W + (long)(ngrp + r) * I_ + kq * 8;

    f32x4 acc[8] = {};
    #pragma unroll
    for (int kc = 0; kc < I_; kc += 32) {
        float4 a0 = *reinterpret_cast<const float4*>(pa + kc);
        float4 a1 = *reinterpret_cast<const float4*>(pa + kc + 4);
        f16x8 af = { (f16)a0.x, (f16)a0.y, (f16)a0.z, (f16)a0.w,
                     (f16)a1.x, (f16)a1.y, (f16)a1.z, (f16)a1.w };
        #pragma unroll
        for (int t = 0; t < 8; ++t) {
            f16x8 wf = *reinterpret_cast<const f16x8*>(pw + (long)t * 16 * I_ + kc);
            acc[t] = __builtin_amdgcn_mfma_f32_16x16x32_f16(af, wf, acc[t], 0, 0, 0);
        }
    }
    const int col = lane & 15, rq = lane >> 4;
    #pragma unroll
    for (int t = 0; t < 8; ++t) {
        const int n = ngrp + t * 16 + col;
        const float bv = bias[n];
        #pragma unroll
        for (int j = 0; j < 4; ++j)
            out[(long)(m0 + rq * 4 + j) * H_ + n] = (f16)(acc[t][j] + bv);
    }
}

// ---------------- persistent dataflow scan — DATA-IS-FLAG ----------------
// 192 WGs x 256 threads, 3 groups of 64 (grp = wg>>6, sub = wg&63):
//   grp0 (mi,ct): h0[ts]  = tanh(xp0[ts] + h0[ts-1]@Whh0^T)
//   grp1 (mi,ct): xp1[ts] = h0[ts]@Wxh1^T + b1
//   grp2 (mi,ct): h1[ts]  = tanh(xp1[ts] + h1[ts-1]@Whh1^T)
// 32-slot rings. Consumers poll the DATA for sentinel (f16 0xFFFF / f32
// 0xFFFFFFFF — unreachable by real values). Producers fire stores and move on
// (no drain, no produce flags): each consumed word self-validates, so
// store->flag ordering is structurally unnecessary. Producer at tp also
// sentinel-resets slot (tp+8)&31 (its OWN addresses; same-thread per-location
// coherence orders reset->rewrite; consumers' data-dependencies put the reset
// >=7 steps in the past => visible). WAR safety: grp1/grp2 publish progress
// every 8 steps; grp0/grp1 check >= ts-16 every 8 steps (16-step slack).
__global__ void __launch_bounds__(256, 1) rnn_scan(
    const float* __restrict__ Whh0, const float* __restrict__ Wxh1, const float* __restrict__ Whh1,
    const f16* __restrict__ xp0, const float* __restrict__ b1,
    u32* __restrict__ ring0, u32* __restrict__ ring1, u32* __restrict__ xp1,
    float* __restrict__ out, int* __restrict__ flags)
{
    extern __shared__ char smem[];                 // 128 KB W + 16 KB part
    float* part = (float*)(smem + 131072);

    const int tid = threadIdx.x;
    const int wave = tid >> 6, lane = tid & 63;
    const int wg = blockIdx.x;
    const int grp = wg >> 6, sub = wg & 63;
    const int mi = sub & 3, ct = sub >> 2;
    const int m0 = mi << 4;
    const int nbase = ct << 6;
    const int r = lane & 15, kq = lane >> 4;

    int* prog1 = flags;             // [4][16] stride 32: grp1 consumed h0 through v-1
    int* prog2 = flags + 2048;      // grp2 consumed xp1 through v-1
    const int mb4 = mi * 16;

    const float* Wmat = (grp == 0) ? Whh0 : (grp == 1) ? Wxh1 : Whh1;

    // ---- one-time: stage W slice (f32 -> f16) into LDS (swizzled 16B chunks) ----
    for (int i = 0; i < 32; ++i) {
        int idx = tid + (i << 8);
        int row = idx >> 7, c = idx & 127;
        const float* src = Wmat + (long)(nbase + row) * H_ + (c << 3);
        float4 w0 = *reinterpret_cast<const float4*>(src);
        float4 w1 = *reinterpret_cast<const float4*>(src + 4);
        f16x8 wf = { (f16)w0.x, (f16)w0.y, (f16)w0.z, (f16)w0.w,
                     (f16)w1.x, (f16)w1.y, (f16)w1.z, (f16)w1.w };
        *reinterpret_cast<f16x8*>(smem + row * 2048 + ((c ^ (row & 7)) << 4)) = wf;
    }
    __syncthreads();

    const int nf = nbase + (wave << 4) + r;        // finalize column
    const float b1v = (grp == 1) ? b1[nf] : 0.f;

    // producer f16 store base (u16 index within slot), + (kq*4+j)*4 per row
    const int kwin_s = nf >> 8, krem_s = nf & 255;
    const int it_s = krem_s >> 5, k32_s = krem_s & 31;
    const int kq3_s = k32_s >> 3, k8_s = k32_s & 7;
    const int base16 = (((mi*4 + kwin_s)*8 + it_s)*256 + (k8_s>>2)*128 + kq3_s*32 + ((k8_s>>1)&1))*2 + (k8_s&1);

    // consumer ring-load base (u32): wave's k-window, lane-linear
    const int cBase = (mi * 4 + wave) * 2048 + (lane << 1);

    for (int ts = 0; ts < T_; ++ts) {
        // ---- batched WAR check (every 8 steps; 16-step slack; spin-guarded) ----
        if ((ts & 7) == 0 && grp != 2 && lane < 16) {
            const int* pf = ((grp == 0) ? prog1 : prog2) + (mb4 + lane) * 32;
            const int thr = ts - 16;
            int g = 0;
            while (ldflag(pf) < thr && ++g < (1 << 20)) {}
        }

        float xv[4];
        // xp0 prefetch (read-only, independent) before the data poll
        if (grp == 0) {
            #pragma unroll
            for (int j = 0; j < 4; ++j)
                xv[j] = (float)xp0[((long)(m0 + kq * 4 + j) * T_ + ts) * H_ + nf];
        } else {
            #pragma unroll
            for (int j = 0; j < 4; ++j) xv[j] = 0.f;
        }

        const u32* abase;
        if (grp == 0)      abase = ring0 + ((ts - 1) & NS_) * RS_ + cBase;
        else if (grp == 1) abase = ring0 + (ts & NS_) * RS_ + cBase;
        else               abase = ring1 + ((ts - 1) & NS_) * RS_ + cBase;

        // ---- data-is-flag poll: reload until every consumed word is non-sentinel ----
        u64 q[8][2];
        if (grp == 2) {
            u32 xw[4];
            const u32* xpb = xp1 + (ts & NS_) * XS_;
            int g = 0; u32 bad;
            do {
                #pragma unroll
                for (int it = 0; it < 8; ++it) {
                    q[it][0] = lda64(abase + it * 256);
                    q[it][1] = lda64(abase + it * 256 + 128);
                }
                #pragma unroll
                for (int j = 0; j < 4; ++j)
                    xw[j] = lda32(xpb + (m0 + kq * 4 + j) * 1024 + nf);
                bad = 0;
                #pragma unroll
                for (int it = 0; it < 8; ++it) { bad |= badq(q[it][0]); bad |= badq(q[it][1]); }
                #pragma unroll
                for (int j = 0; j < 4; ++j) bad |= (xw[j] == 0xFFFFFFFFu) ? 1u : 0u;
            } while (__any(bad != 0) && ++g < (1 << 16));
            #pragma unroll
            for (int j = 0; j < 4; ++j) xv[j] = __builtin_bit_cast(float, xw[j]);
        } else {
            int g = 0; u32 bad;
            do {
                #pragma unroll
                for (int it = 0; it < 8; ++it) {
                    q[it][0] = lda64(abase + it * 256);
                    q[it][1] = lda64(abase + it * 256 + 128);
                }
                bad = 0;
                #pragma unroll
                for (int it = 0; it < 8; ++it) { bad |= badq(q[it][0]); bad |= badq(q[it][1]); }
            } while (__any(bad != 0) && ++g < (1 << 16));
        }

        // ---- unpack + MFMA (operands bit-identical to r12/r15) ----
        f16x8 ah[8];
        #pragma unroll
        for (int it = 0; it < 8; ++it) {
            u32 w0 = (u32)q[it][0], w1 = (u32)(q[it][0] >> 32);
            u32 w2 = (u32)q[it][1], w3 = (u32)(q[it][1] >> 32);
            ah[it][0] = __builtin_bit_cast(f16, (u16)(w0 & 0xffff));
            ah[it][1] = __builtin_bit_cast(f16, (u16)(w0 >> 16));
            ah[it][2] = __builtin_bit_cast(f16, (u16)(w1 & 0xffff));
            ah[it][3] = __builtin_bit_cast(f16, (u16)(w1 >> 16));
            ah[it][4] = __builtin_bit_cast(f16, (u16)(w2 & 0xffff));
            ah[it][5] = __builtin_bit_cast(f16, (u16)(w2 >> 16));
            ah[it][6] = __builtin_bit_cast(f16, (u16)(w3 & 0xffff));
            ah[it][7] = __builtin_bit_cast(f16, (u16)(w3 >> 16));
        }

        f32x4 acc[4] = {};
        #pragma unroll
        for (int it = 0; it < 8; ++it) {
            #pragma unroll
            for (int t = 0; t < 4; ++t) {
                f16x8 wf = *reinterpret_cast<const f16x8*>(
                    smem + (t * 16 + r) * 2048
                         + ((((wave << 5) + (it << 2) + kq) ^ (r & 7)) << 4));
                acc[t] = __builtin_amdgcn_mfma_f32_16x16x32_f16(ah[it], wf, acc[t], 0, 0, 0);
            }
        }
        #pragma unroll
        for (int t = 0; t < 4; ++t)
            *reinterpret_cast<f32x4*>(&part[((wave << 2) + t) * 256 + (lane << 2)]) = acc[t];
        __syncthreads();

        // batched progress publish (consumption of this step's inputs is complete)
        if ((ts & 7) == 7 && tid == 0) {
            if (grp == 1)      stflag(prog1 + (mb4 + ct) * 32, ts + 1);
            else if (grp == 2) stflag(prog2 + (mb4 + ct) * 32, ts + 1);
        }

        {
            f32x4 sm = *reinterpret_cast<f32x4*>(&part[wave * 256 + (lane << 2)]);
            #pragma unroll
            for (int w2 = 1; w2 < 4; ++w2)
                sm = sm + *reinterpret_cast<f32x4*>(&part[((w2 << 2) + wave) * 256 + (lane << 2)]);
            const int dSlot = (ts & NS_), rSlot = ((ts + RL_) & NS_);
            #pragma unroll
            for (int j = 0; j < 4; ++j) {
                const int b = m0 + kq * 4 + j;
                float v = sm[j];
                if (grp == 0) {
                    v = tanhf(v + xv[j]);
                    u16* p0 = (u16*)ring0;
                    sta16(p0 + dSlot * RS_ * 2 + base16 + (kq * 4 + j) * 4,
                          __builtin_bit_cast(u16, (f16)v));
                    sta16(p0 + rSlot * RS_ * 2 + base16 + (kq * 4 + j) * 4, (u16)0xFFFFu);
                    if (ts == T_ - 1) out[(long)B_ * T_ * H_ + (long)b * H_ + nf] = v;
                } else if (grp == 1) {
                    sta32(xp1 + dSlot * XS_ + b * 1024 + nf,
                          __builtin_bit_cast(u32, v + b1v));
                    sta32(xp1 + rSlot * XS_ + b * 1024 + nf, 0xFFFFFFFFu);
                } else {
                    v = tanhf(v + xv[j]);
                    u16* p1 = (u16*)ring1;
                    sta16(p1 + dSlot * RS_ * 2 + base16 + (kq * 4 + j) * 4,
                          __builtin_bit_cast(u16, (f16)v));
                    sta16(p1 + rSlot * RS_ * 2 + base16 + (kq * 4 + j) * 4, (u16)0xFFFFu);
                    out[((long)b * T_ + ts) * H_ + nf] = v;
                    if (ts == T_ - 1) out[(long)B_ * T_ * H_ + HB_ + (long)b * H_ + nf] = v;
                }
            }
        }
        // no drain, no produce flag — fire and loop. Barrier only for LDS part[] reuse.
        __syncthreads();
    }
}

// ---------------- host launcher ----------------
extern "C" void kernel_launch(void* const* d_in, const int* in_sizes, int n_in,
                              void* d_out, int out_size, void* d_ws, size_t ws_size,
                              hipStream_t stream) {
    const float* x    = (const float*)d_in[0];
    const float* h0   = (const float*)d_in[1];
    const float* Wxh0 = (const float*)d_in[2];
    const float* Whh0 = (const float*)d_in[3];
    const float* b0   = (const float*)d_in[4];
    const float* Wxh1 = (const float*)d_in[5];
    const float* Whh1 = (const float*)d_in[6];
    const float* b1   = (const float*)d_in[7];
    float* out = (float*)d_out;

    char* ws = (char*)d_ws;
    const long MB = 1024 * 1024;
    f16* Wxh0h = (f16*)(ws + 0);            // 1 MB
    int* flags = (int*)(ws + 2*MB);         // prog1/prog2 (<64 KB)
    u32* ring0 = (u32*)(ws + 4*MB);         // 32 slots x 128 KB = 4 MB
    u32* ring1 = (u32*)(ws + 8*MB);         // 4 MB
    u32* xp1   = (u32*)(ws + 12*MB);        // 32 slots x 256 KB f32 = 8 MB
    f16* xp0   = (f16*)(ws + 20*MB);        // [B][T][H] f16, 64 MB  (end: 84 MB)

    hipMemsetAsync(flags, 0, 64*1024, stream);
    hipMemsetAsync(ws + 4*MB, 0xFF, 16*MB, stream);     // rings + xp1 -> sentinel
    cvt_f16<<<512, 256, 0, stream>>>(Wxh0, Wxh0h, (long)H_*I_);
    init_rings<<<HB_/256, 256, 0, stream>>>(h0, (u16*)ring0, (u16*)ring1);

    // xp0 = x @ Wxh0^T + b0   (row index = b*T + t)
    gemm_xproj<<<dim3((B_*T_)/16, H_/512), 256, 0, stream>>>(x, Wxh0h, b0, xp0);

    hipFuncSetAttribute((const void*)rnn_scan,
                        hipFuncAttributeMaxDynamicSharedMemorySize, 147456);

    void* args[] = { (void*)&Whh0, (void*)&Wxh1, (void*)&Whh1, (void*)&xp0,
                     (void*)&b1, (void*)&ring0, (void*)&ring1, (void*)&xp1,
                     (void*)&out, (void*)&flags };
    hipLaunchCooperativeKernel((void*)rnn_scan, dim3(NWG_), dim3(256), args,
                               147456, stream);
}